// Round 1
// baseline (204.991 us; speedup 1.0000x reference)
//
#include <hip/hip_runtime.h>
#include <math.h>

#define N_ROWS 131072
#define DIM 1024
#define KNNK 32
#define SEL1_BLOCKS 128   // each handles 1024 rows
#define CAND_PER_CLASS (SEL1_BLOCKS * KNNK)  // 4096

__device__ __forceinline__ float wave_sum(float v) {
#pragma unroll
  for (int off = 32; off > 0; off >>= 1) v += __shfl_xor(v, off, 64);
  return v;
}

// ---------------- kernel 1: my[j] = (q[j]-mean(q))^2 ----------------
__global__ void k_my(const float* __restrict__ q, float* __restrict__ my) {
  __shared__ float red[256];
  int t = threadIdx.x;
  float4 v = reinterpret_cast<const float4*>(q)[t];  // 256*4 = 1024
  float s = v.x + v.y + v.z + v.w;
  red[t] = s;
  __syncthreads();
  for (int off = 128; off > 0; off >>= 1) {
    if (t < off) red[t] += red[t + off];
    __syncthreads();
  }
  float mean = red[0] * (1.0f / DIM);
  float4 m;
  m.x = (v.x - mean) * (v.x - mean);
  m.y = (v.y - mean) * (v.y - mean);
  m.z = (v.z - mean) * (v.z - mean);
  m.w = (v.w - mean) * (v.w - mean);
  reinterpret_cast<float4*>(my)[t] = m;
}

// ---------------- kernel 2: kl[i] = sum_j |(A[i,j]-mean_i)^2 - my[j]| -------
__global__ void __launch_bounds__(256) k_kl(const float* __restrict__ A,
                                            const float* __restrict__ my,
                                            float* __restrict__ kl) {
  int t = threadIdx.x;
  int lane = t & 63;
  int gw = blockIdx.x * (blockDim.x >> 6) + (t >> 6);
  int nw = gridDim.x * (blockDim.x >> 6);
  const float4* MY = reinterpret_cast<const float4*>(my);
  float4 m0 = MY[lane], m1 = MY[64 + lane], m2 = MY[128 + lane], m3 = MY[192 + lane];
  const float4* A4 = reinterpret_cast<const float4*>(A);
  for (int row = gw; row < N_ROWS; row += nw) {
    int rb = row * 256;
    float4 a0 = A4[rb + lane];
    float4 a1 = A4[rb + 64 + lane];
    float4 a2 = A4[rb + 128 + lane];
    float4 a3 = A4[rb + 192 + lane];
    float s = a0.x + a0.y + a0.z + a0.w
            + a1.x + a1.y + a1.z + a1.w
            + a2.x + a2.y + a2.z + a2.w
            + a3.x + a3.y + a3.z + a3.w;
    s = wave_sum(s);
    float mean = s * (1.0f / DIM);
    float d, p = 0.0f;
    d = a0.x - mean; p += fabsf(d * d - m0.x);
    d = a0.y - mean; p += fabsf(d * d - m0.y);
    d = a0.z - mean; p += fabsf(d * d - m0.z);
    d = a0.w - mean; p += fabsf(d * d - m0.w);
    d = a1.x - mean; p += fabsf(d * d - m1.x);
    d = a1.y - mean; p += fabsf(d * d - m1.y);
    d = a1.z - mean; p += fabsf(d * d - m1.z);
    d = a1.w - mean; p += fabsf(d * d - m1.w);
    d = a2.x - mean; p += fabsf(d * d - m2.x);
    d = a2.y - mean; p += fabsf(d * d - m2.y);
    d = a2.z - mean; p += fabsf(d * d - m2.z);
    d = a2.w - mean; p += fabsf(d * d - m2.w);
    d = a3.x - mean; p += fabsf(d * d - m3.x);
    d = a3.y - mean; p += fabsf(d * d - m3.y);
    d = a3.z - mean; p += fabsf(d * d - m3.z);
    d = a3.w - mean; p += fabsf(d * d - m3.w);
    p = wave_sum(p);
    if (lane == 0) kl[row] = p;
  }
}

// ---------------- kernel 3: per-block per-class 32 smallest ----------------
// grid = SEL1_BLOCKS, block = 256. Block b handles kl[b*1024 .. +1023].
__global__ void __launch_bounds__(256) k_sel1(const float* __restrict__ kl,
                                              const int* __restrict__ lab,
                                              float* __restrict__ cand) {
  int b = blockIdx.x, t = threadIdx.x;
  int base = b * 1024 + t * 4;
  float4 v = *reinterpret_cast<const float4*>(kl + base);
  int4 lb = *reinterpret_cast<const int4*>(lab + base);
  float vv[4] = {v.x, v.y, v.z, v.w};
  int ll[4] = {lb.x, lb.y, lb.z, lb.w};

  __shared__ float wval[4];
  __shared__ int widx[4];
  __shared__ int winI;

  for (int c = 0; c < 2; ++c) {
    float w0 = (ll[0] == c) ? vv[0] : INFINITY;
    float w1 = (ll[1] == c) ? vv[1] : INFINITY;
    float w2 = (ll[2] == c) ? vv[2] : INFINITY;
    float w3 = (ll[3] == c) ? vv[3] : INFINITY;
    for (int it = 0; it < KNNK; ++it) {
      float mv = w0; int mi = 0;
      if (w1 < mv) { mv = w1; mi = 1; }
      if (w2 < mv) { mv = w2; mi = 2; }
      if (w3 < mv) { mv = w3; mi = 3; }
      int gi = t * 4 + mi;
#pragma unroll
      for (int off = 32; off > 0; off >>= 1) {
        float ov = __shfl_xor(mv, off, 64);
        int oi = __shfl_xor(gi, off, 64);
        if (ov < mv || (ov == mv && oi < gi)) { mv = ov; gi = oi; }
      }
      int wid = t >> 6;
      if ((t & 63) == 0) { wval[wid] = mv; widx[wid] = gi; }
      __syncthreads();
      if (t == 0) {
        float bv = wval[0]; int bi = widx[0];
#pragma unroll
        for (int k = 1; k < 4; ++k)
          if (wval[k] < bv || (wval[k] == bv && widx[k] < bi)) { bv = wval[k]; bi = widx[k]; }
        winI = bi;
        cand[(c * SEL1_BLOCKS + b) * KNNK + it] = bv;
      }
      __syncthreads();
      int wi = winI;
      bool mine = ((wi >> 2) == t);
      int k = wi & 3;
      w0 = (mine && k == 0) ? INFINITY : w0;
      w1 = (mine && k == 1) ? INFINITY : w1;
      w2 = (mine && k == 2) ? INFINITY : w2;
      w3 = (mine && k == 3) ? INFINITY : w3;
    }
  }
}

// ---------------- kernel 4: per-class 32 smallest of 4096 candidates -------
// grid = 2 (one block per class), block = 256.
__global__ void __launch_bounds__(256) k_sel2(const float* __restrict__ cand,
                                              float* __restrict__ s32,
                                              float* __restrict__ idm) {
  int c = blockIdx.x, t = threadIdx.x;
  const float* src = cand + c * CAND_PER_CLASS;
  float w[16];
#pragma unroll
  for (int k = 0; k < 16; ++k) w[k] = src[t + 256 * k];

  __shared__ float wval[4];
  __shared__ int widx[4];
  __shared__ int winI;
  __shared__ float sel[KNNK];

  for (int it = 0; it < KNNK; ++it) {
    float mv = w[0]; int mi = 0;
#pragma unroll
    for (int k = 1; k < 16; ++k)
      if (w[k] < mv) { mv = w[k]; mi = k; }
    int gi = mi * 256 + t;
#pragma unroll
    for (int off = 32; off > 0; off >>= 1) {
      float ov = __shfl_xor(mv, off, 64);
      int oi = __shfl_xor(gi, off, 64);
      if (ov < mv || (ov == mv && oi < gi)) { mv = ov; gi = oi; }
    }
    int wid = t >> 6;
    if ((t & 63) == 0) { wval[wid] = mv; widx[wid] = gi; }
    __syncthreads();
    if (t == 0) {
      float bv = wval[0]; int bi = widx[0];
#pragma unroll
      for (int k = 1; k < 4; ++k)
        if (wval[k] < bv || (wval[k] == bv && widx[k] < bi)) { bv = wval[k]; bi = widx[k]; }
      winI = bi;
      sel[it] = bv;
    }
    __syncthreads();
    int wi = winI;
    bool mine = ((wi & 255) == t);
    int sk = wi >> 8;
#pragma unroll
    for (int k = 0; k < 16; ++k)
      w[k] = (mine && k == sk) ? INFINITY : w[k];
  }
  if (t < KNNK) s32[c * KNNK + t] = sel[t];
  if (t == 0) {
    float s = 0.0f;
#pragma unroll
    for (int k = 0; k < KNNK; ++k) s += sel[k];
    idm[c] = s * (1.0f / KNNK);
  }
}

// ---------------- kernel 5: score normalize + 32-NN vote -------------------
__global__ void k_final(const float* __restrict__ s32,
                        const float* __restrict__ idm,
                        float* __restrict__ out) {
  if (threadIdx.x != 0 || blockIdx.x != 0) return;
  float id0 = idm[0], id1 = idm[1];
  float denom = fmaxf(fabsf(id0) + fabsf(id1), 1e-12f);
  const float* a = s32;        // class 0, ascending
  const float* b = s32 + KNNK; // class 1, ascending
  int i = 0, j = 0;
  for (int k = 0; k < KNNK; ++k) {
    if (j >= KNNK || (i < KNNK && a[i] <= b[j])) ++i; else ++j;
  }
  // knn_cnt = [i, 32-i]; argmax first-wins -> tie (16/16) gives class 0
  int pred = (i >= KNNK / 2) ? 0 : 1;
  out[0] = (float)pred;
  out[1] = id0 / denom;
  out[2] = id1 / denom;
}

extern "C" void kernel_launch(void* const* d_in, const int* in_sizes, int n_in,
                              void* d_out, int out_size, void* d_ws, size_t ws_size,
                              hipStream_t stream) {
  const float* query = (const float*)d_in[0];
  const float* anchor = (const float*)d_in[1];
  const int* label = (const int*)d_in[2];
  float* out = (float*)d_out;

  float* ws = (float*)d_ws;
  float* my = ws;                          // 1024
  float* kl = ws + 1024;                   // 131072
  float* cand = ws + 1024 + N_ROWS;        // 2*4096
  float* s32 = cand + 2 * CAND_PER_CLASS;  // 64
  float* idm = s32 + 64;                   // 2

  k_my<<<1, 256, 0, stream>>>(query, my);
  k_kl<<<2048, 256, 0, stream>>>(anchor, my, kl);
  k_sel1<<<SEL1_BLOCKS, 256, 0, stream>>>(kl, label, cand);
  k_sel2<<<2, 256, 0, stream>>>(cand, s32, idm);
  k_final<<<1, 64, 0, stream>>>(s32, idm, out);
}

// Round 2
// 203.084 us; speedup vs baseline: 1.0094x; 1.0094x over previous
//
#include <hip/hip_runtime.h>
#include <math.h>

#define N_ROWS 131072
#define DIM 1024
#define KNNK 32
#define NW1 128                      // k_sel1 waves (1 per block)
#define ROWS_PER_W (N_ROWS / NW1)    // 1024 rows per sel1 wave
#define CANDS (NW1 * KNNK)           // 4096 candidates per class

__device__ __forceinline__ float wave_sum(float v) {
#pragma unroll
  for (int off = 32; off > 0; off >>= 1) v += __shfl_xor(v, off, 64);
  return v;
}

__device__ __forceinline__ float4 sqdiff(float4 a, float m) {
  float4 r;
  r.x = (a.x - m) * (a.x - m);
  r.y = (a.y - m) * (a.y - m);
  r.z = (a.z - m) * (a.z - m);
  r.w = (a.w - m) * (a.w - m);
  return r;
}

// ---- kernel 1: kl[i] = sum_j |(A[i,j]-mean_i)^2 - (q[j]-mean_q)^2| --------
// Wave-autonomous: each wave computes the query moment table into registers
// (query is L2-hot, ~4KB/wave), then grid-strides rows. No LDS, no barriers.
__global__ void __launch_bounds__(256) k_kl(const float* __restrict__ A,
                                            const float* __restrict__ q,
                                            float* __restrict__ kl) {
  int t = threadIdx.x;
  int lane = t & 63;
  int gw = blockIdx.x * (blockDim.x >> 6) + (t >> 6);
  int nw = gridDim.x * (blockDim.x >> 6);

  const float4* Q4 = reinterpret_cast<const float4*>(q);
  float4 q0 = Q4[lane], q1 = Q4[64 + lane], q2 = Q4[128 + lane], q3 = Q4[192 + lane];
  float qs = q0.x + q0.y + q0.z + q0.w
           + q1.x + q1.y + q1.z + q1.w
           + q2.x + q2.y + q2.z + q2.w
           + q3.x + q3.y + q3.z + q3.w;
  qs = wave_sum(qs);
  float qm = qs * (1.0f / DIM);
  float4 m0 = sqdiff(q0, qm), m1 = sqdiff(q1, qm),
         m2 = sqdiff(q2, qm), m3 = sqdiff(q3, qm);

  const float4* A4 = reinterpret_cast<const float4*>(A);
  for (int row = gw; row < N_ROWS; row += nw) {
    int rb = row * 256;
    float4 a0 = A4[rb + lane];
    float4 a1 = A4[rb + 64 + lane];
    float4 a2 = A4[rb + 128 + lane];
    float4 a3 = A4[rb + 192 + lane];
    float s = a0.x + a0.y + a0.z + a0.w
            + a1.x + a1.y + a1.z + a1.w
            + a2.x + a2.y + a2.z + a2.w
            + a3.x + a3.y + a3.z + a3.w;
    s = wave_sum(s);
    float mean = s * (1.0f / DIM);
    float d, p = 0.0f;
    d = a0.x - mean; p += fabsf(d * d - m0.x);
    d = a0.y - mean; p += fabsf(d * d - m0.y);
    d = a0.z - mean; p += fabsf(d * d - m0.z);
    d = a0.w - mean; p += fabsf(d * d - m0.w);
    d = a1.x - mean; p += fabsf(d * d - m1.x);
    d = a1.y - mean; p += fabsf(d * d - m1.y);
    d = a1.z - mean; p += fabsf(d * d - m1.z);
    d = a1.w - mean; p += fabsf(d * d - m1.w);
    d = a2.x - mean; p += fabsf(d * d - m2.x);
    d = a2.y - mean; p += fabsf(d * d - m2.y);
    d = a2.z - mean; p += fabsf(d * d - m2.z);
    d = a2.w - mean; p += fabsf(d * d - m2.w);
    d = a3.x - mean; p += fabsf(d * d - m3.x);
    d = a3.y - mean; p += fabsf(d * d - m3.y);
    d = a3.z - mean; p += fabsf(d * d - m3.z);
    d = a3.w - mean; p += fabsf(d * d - m3.w);
    p = wave_sum(p);
    if (lane == 0) kl[row] = p;
  }
}

// ---- kernel 2: per-wave per-class 32 smallest (barrier-free) --------------
// grid = NW1 blocks x 64 threads. Wave w owns rows [w*1024, w*1024+1024).
// Outputs sorted-ascending 32 values per class: cand[c*CANDS + w*32 + it].
__global__ void __launch_bounds__(64) k_sel1(const float* __restrict__ kl,
                                             const int* __restrict__ lab,
                                             float* __restrict__ cand) {
  int w = blockIdx.x;
  int lane = threadIdx.x;
  int base = w * ROWS_PER_W;
  float v[16];
  int lb[16];
#pragma unroll
  for (int k = 0; k < 16; ++k) {
    v[k] = kl[base + k * 64 + lane];
    lb[k] = lab[base + k * 64 + lane];
  }
  for (int c = 0; c < 2; ++c) {
    float wv[16];
#pragma unroll
    for (int k = 0; k < 16; ++k) wv[k] = (lb[k] == c) ? v[k] : INFINITY;
    for (int it = 0; it < KNNK; ++it) {
      float mv = wv[0];
      int mi = 0;
#pragma unroll
      for (int k = 1; k < 16; ++k)
        if (wv[k] < mv) { mv = wv[k]; mi = k; }
      int gi = mi * 64 + lane;
#pragma unroll
      for (int off = 32; off > 0; off >>= 1) {
        float ov = __shfl_xor(mv, off, 64);
        int oi = __shfl_xor(gi, off, 64);
        if (ov < mv || (ov == mv && oi < gi)) { mv = ov; gi = oi; }
      }
      if (lane == 0) cand[(c * NW1 + w) * KNNK + it] = mv;
      int kw = gi >> 6, lw = gi & 63;
#pragma unroll
      for (int k = 0; k < 16; ++k)
        wv[k] = (lane == lw && k == kw) ? INFINITY : wv[k];
    }
  }
}

// ---- kernel 3: final select + merge + vote (single block, 512 thr) --------
// Waves 0-3: class 0 quarters (1024 cands -> sorted 32 each).
// Waves 4-7: class 1 quarters. Barrier. Waves 0/4 merge 128 -> 32 + mean.
// Barrier. Wave 0: merge-path ballot vote + normalize + write out[3].
__global__ void __launch_bounds__(512) k_sel2f(const float* __restrict__ cand,
                                               float* __restrict__ out) {
  int t = threadIdx.x;
  int lane = t & 63, wid = t >> 6;
  int c = wid >> 2, qtr = wid & 3;
  const float* src = cand + c * CANDS + qtr * 1024;

  __shared__ float s1[2][4][KNNK];
  __shared__ float s2[2][KNNK];
  __shared__ float idm[2];

  float wv[16];
#pragma unroll
  for (int k = 0; k < 16; ++k) wv[k] = src[k * 64 + lane];
  for (int it = 0; it < KNNK; ++it) {
    float mv = wv[0];
    int mi = 0;
#pragma unroll
    for (int k = 1; k < 16; ++k)
      if (wv[k] < mv) { mv = wv[k]; mi = k; }
    int gi = mi * 64 + lane;
#pragma unroll
    for (int off = 32; off > 0; off >>= 1) {
      float ov = __shfl_xor(mv, off, 64);
      int oi = __shfl_xor(gi, off, 64);
      if (ov < mv || (ov == mv && oi < gi)) { mv = ov; gi = oi; }
    }
    if (lane == 0) s1[c][qtr][it] = mv;
    int kw = gi >> 6, lw = gi & 63;
#pragma unroll
    for (int k = 0; k < 16; ++k)
      wv[k] = (lane == lw && k == kw) ? INFINITY : wv[k];
  }
  __syncthreads();

  if ((wid & 3) == 0) {  // waves 0 and 4: merge 128 -> 32 for class c
    const float* m = &s1[c][0][0];
    float a0 = m[lane], a1 = m[64 + lane];
    float sum = 0.0f;
    for (int it = 0; it < KNNK; ++it) {
      float mv;
      int mi;
      if (a0 < a1 || (a0 == a1)) { mv = a0; mi = 0; } else { mv = a1; mi = 1; }
      int gi = mi * 64 + lane;
#pragma unroll
      for (int off = 32; off > 0; off >>= 1) {
        float ov = __shfl_xor(mv, off, 64);
        int oi = __shfl_xor(gi, off, 64);
        if (ov < mv || (ov == mv && oi < gi)) { mv = ov; gi = oi; }
      }
      if (lane == 0) s2[c][it] = mv;
      sum += mv;  // all lanes hold the winner after the butterfly
      int kw = gi >> 6, lw = gi & 63;
      a0 = (lane == lw && kw == 0) ? INFINITY : a0;
      a1 = (lane == lw && kw == 1) ? INFINITY : a1;
    }
    if (lane == 0) idm[c] = sum * (1.0f / KNNK);
  }
  __syncthreads();

  if (wid == 0) {
    // merge-path: n = #(class-0 entries among global 32 smallest)
    float av = (lane < KNNK) ? s2[0][lane] : 0.0f;
    float bv = (lane < KNNK) ? s2[1][KNNK - 1 - lane] : 1.0f;
    unsigned long long blt = __ballot(lane < KNNK && av <= bv);
    int n = __popcll(blt);
    if (lane == 0) {
      float id0 = idm[0], id1 = idm[1];
      float denom = fmaxf(fabsf(id0) + fabsf(id1), 1e-12f);
      out[0] = (n >= KNNK / 2) ? 0.0f : 1.0f;  // argmax, first-wins on tie
      out[1] = id0 / denom;
      out[2] = id1 / denom;
    }
  }
}

extern "C" void kernel_launch(void* const* d_in, const int* in_sizes, int n_in,
                              void* d_out, int out_size, void* d_ws, size_t ws_size,
                              hipStream_t stream) {
  const float* query = (const float*)d_in[0];
  const float* anchor = (const float*)d_in[1];
  const int* label = (const int*)d_in[2];
  float* out = (float*)d_out;

  float* ws = (float*)d_ws;
  float* kl = ws;                    // 131072
  float* cand = ws + N_ROWS;         // 2*4096

  k_kl<<<2048, 256, 0, stream>>>(anchor, query, kl);
  k_sel1<<<NW1, 64, 0, stream>>>(kl, label, cand);
  k_sel2f<<<1, 512, 0, stream>>>(cand, out);
}